// Round 6
// baseline (414.382 us; speedup 1.0000x reference)
//
#include <hip/hip_runtime.h>
#include <hip/hip_bf16.h>

#define N_DRUG 20000
#define N_DIS  40000
#define NE     500000
#define D      128
#define PITCH  136   // bf16 elems per LDS row (16B-aligned; 2-way bank alias = free)
#define NTOT   100000  // concatenated node slots: ind(40k) | dd(40k) | rev(20k)

typedef __hip_bfloat16 bf16;
typedef __attribute__((ext_vector_type(8))) short short8;
typedef __attribute__((ext_vector_type(4))) float floatx4;

__device__ __forceinline__ float b2f(bf16 x) { return __bfloat162float(x); }

// MFMA GEMM: Wh(bf16) = feat(f32->bf16) @ W(f32->bf16) + b, plus per-row scalars
// s1 = Wh . a1, s2 = Wh . a2. Block = 256 thr (4 waves) = 64 rows x 128 cols.
__global__ void k_gemm_mfma(const float* __restrict__ feat, int M,
                            const float* __restrict__ W, const float* __restrict__ bias,
                            const float* __restrict__ a1, const float* __restrict__ a2,
                            bf16* __restrict__ Wh, float* __restrict__ s1,
                            float* __restrict__ s2)
{
    __shared__ __align__(16) bf16 WT[128 * PITCH];  // WT[n][k] = W[k][n]
    __shared__ __align__(16) bf16 FS[64 * PITCH];   // FS[r][k] = feat[row0+r][k]
    const int tid  = threadIdx.x;
    const int row0 = blockIdx.x * 64;

#pragma unroll 4
    for (int rep = 0; rep < 64; ++rep) {
        int idx = rep * 256 + tid;           // k*128+n
        int k = idx >> 7, n = idx & 127;
        WT[n * PITCH + k] = __float2bfloat16(W[idx]);
    }
#pragma unroll 4
    for (int rep = 0; rep < 32; ++rep) {
        int idx = rep * 256 + tid;           // r*128+k
        int r = idx >> 7, k = idx & 127;
        int gr = row0 + r;
        float v = (gr < M) ? feat[(size_t)gr * D + k] : 0.f;
        FS[r * PITCH + k] = __float2bfloat16(v);
    }
    __syncthreads();

    const int wave = tid >> 6;
    const int lane = tid & 63;
    const int m0   = wave * 16;
    const int arow = lane & 15;
    const int kq   = lane >> 4;

    floatx4 acc[8];
#pragma unroll
    for (int t = 0; t < 8; ++t) acc[t] = (floatx4){0.f, 0.f, 0.f, 0.f};

#pragma unroll
    for (int ks = 0; ks < 4; ++ks) {
        const int kb = ks * 32 + kq * 8;
        short8 afrag = *(const short8*)(FS + (m0 + arow) * PITCH + kb);
#pragma unroll
        for (int t = 0; t < 8; ++t) {
            short8 bfrag = *(const short8*)(WT + (t * 16 + arow) * PITCH + kb);
            acc[t] = __builtin_amdgcn_mfma_f32_16x16x32_bf16(afrag, bfrag, acc[t], 0, 0, 0);
        }
    }

    const int crow = m0 + kq * 4;
    float p1[4] = {0.f, 0.f, 0.f, 0.f};
    float p2[4] = {0.f, 0.f, 0.f, 0.f};
#pragma unroll
    for (int t = 0; t < 8; ++t) {
        const int n = t * 16 + arow;
        const float bn = bias[n], a1n = a1[n], a2n = a2[n];
#pragma unroll
        for (int r = 0; r < 4; ++r) {
            float v = acc[t][r] + bn;
            int gr = row0 + crow + r;
            if (gr < M) Wh[(size_t)gr * D + n] = __float2bfloat16(v);
            p1[r] += v * a1n;
            p2[r] += v * a2n;
        }
    }
#pragma unroll
    for (int r = 0; r < 4; ++r) {
#pragma unroll
        for (int off = 1; off < 16; off <<= 1) {
            p1[r] += __shfl_xor(p1[r], off);
            p2[r] += __shfl_xor(p2[r], off);
        }
    }
    if (arow == 0) {
#pragma unroll
        for (int r = 0; r < 4; ++r) {
            int gr = row0 + crow + r;
            if (gr < M) { s1[gr] = p1[r]; s2[gr] = p2[r]; }
        }
    }
}

// Fused histogram over all 3 etypes into one concatenated cnt[NTOT].
__global__ void k_hist3(const int* __restrict__ d_ind, const int* __restrict__ d_dd,
                        const int* __restrict__ d_rev, int* __restrict__ cnt)
{
    int i = blockIdx.x * blockDim.x + threadIdx.x;
    if (i < NE)          atomicAdd(&cnt[d_ind[i]], 1);
    else if (i < 2 * NE) atomicAdd(&cnt[40000 + d_dd[i - NE]], 1);
    else if (i < 3 * NE) atomicAdd(&cnt[80000 + d_rev[i - 2 * NE]], 1);
}

// One scan over the concatenated cnt: segment order across the col pool is
// arbitrary, so a single global cursor works for all three etypes.
__global__ void k_base(const int* __restrict__ cnt, int* __restrict__ base,
                       int* __restrict__ cursor, int* __restrict__ total, int n)
{
    __shared__ int sd[256];
    __shared__ int sbase;
    const int tid = threadIdx.x;
    const int gid = blockIdx.x * 256 + tid;
    int c = (gid < n) ? cnt[gid] : 0;
    sd[tid] = c;
    __syncthreads();
    for (int off = 1; off < 256; off <<= 1) {
        int v = (tid >= off) ? sd[tid - off] : 0;
        __syncthreads();
        sd[tid] += v;
        __syncthreads();
    }
    if (tid == 255) sbase = atomicAdd(total, sd[255]);
    __syncthreads();
    if (gid < n) {
        int b = sbase + sd[tid] - c;
        base[gid]   = b;
        cursor[gid] = b;
    }
}

// Fused CSR fill for all 3 etypes into one col pool.
__global__ void k_fill3(const int* __restrict__ s_ind, const int* __restrict__ d_ind,
                        const int* __restrict__ s_dd,  const int* __restrict__ d_dd,
                        const int* __restrict__ s_rev, const int* __restrict__ d_rev,
                        int* __restrict__ cursor, int* __restrict__ col)
{
    int i = blockIdx.x * blockDim.x + threadIdx.x;
    if (i < NE) {
        int pos = atomicAdd(&cursor[d_ind[i]], 1);
        col[pos] = s_ind[i];
    } else if (i < 2 * NE) {
        int j = i - NE;
        int pos = atomicAdd(&cursor[40000 + d_dd[j]], 1);
        col[pos] = s_dd[j];
    } else if (i < 3 * NE) {
        int j = i - 2 * NE;
        int pos = atomicAdd(&cursor[80000 + d_rev[j]], 1);
        col[pos] = s_rev[j];
    }
}

// Softmax-weighted gather over one CSR segment; returns normalized (x,y) for
// this lane's 2 dims. 64-edge batches, 4x-unrolled broadcast inner loop.
__device__ __forceinline__ float2 agg_seg(int b, int c, const int* __restrict__ col,
                                          const float* __restrict__ ssrc, float sdv,
                                          const bf16* __restrict__ Whs, int lane)
{
    float ax = 0.f, ay = 0.f, dpart = 0.f;
    for (int t0 = 0; t0 < c; t0 += 64) {
        const int rem = c - t0;
        const int k = rem < 64 ? rem : 64;
        int myc = 0; float myex = 0.f;
        if (lane < k) {
            myc = col[b + t0 + lane];
            float e = ssrc[myc] + sdv;
            e = (e >= 0.f) ? e : 0.01f * e;
            myex = __expf(fminf(e, 30.f));
        }
        dpart += myex;
        const int kk = (k + 3) & ~3;
        for (int j = 0; j < kk; j += 4) {
            int   s0 = __shfl(myc, j),      s1v = __shfl(myc, j + 1);
            int   s2v = __shfl(myc, j + 2), s3v = __shfl(myc, j + 3);
            float e0 = __shfl(myex, j),     e1 = __shfl(myex, j + 1);
            float e2 = __shfl(myex, j + 2), e3 = __shfl(myex, j + 3);
            __hip_bfloat162 w0 = *(const __hip_bfloat162*)(Whs + (size_t)s0 * D + 2 * lane);
            __hip_bfloat162 w1 = *(const __hip_bfloat162*)(Whs + (size_t)s1v * D + 2 * lane);
            __hip_bfloat162 w2 = *(const __hip_bfloat162*)(Whs + (size_t)s2v * D + 2 * lane);
            __hip_bfloat162 w3 = *(const __hip_bfloat162*)(Whs + (size_t)s3v * D + 2 * lane);
            ax += e0 * b2f(w0.x) + e1 * b2f(w1.x) + e2 * b2f(w2.x) + e3 * b2f(w3.x);
            ay += e0 * b2f(w0.y) + e1 * b2f(w1.y) + e2 * b2f(w2.y) + e3 * b2f(w3.y);
        }
    }
    float denom = dpart;
#pragma unroll
    for (int off = 32; off; off >>= 1) denom += __shfl_xor(denom, off);
    const float inv = (c > 0) ? 1.f / denom : 0.f;
    return make_float2(ax * inv, ay * inv);
}

// h_dis = softmax_agg(ind) + softmax_agg(dd), fused: one wave per dis node.
__global__ void k_agg_dis(const int* __restrict__ base, const int* __restrict__ cnt,
                          const int* __restrict__ col,
                          const float* __restrict__ ss_ind, const float* __restrict__ sd_ind,
                          const bf16* __restrict__ Wh_ind,
                          const float* __restrict__ ss_dd, const float* __restrict__ sd_dd,
                          const bf16* __restrict__ Wh_dd,
                          float* __restrict__ out)
{
    const int g    = (int)((blockIdx.x * blockDim.x + threadIdx.x) >> 6);
    const int lane = threadIdx.x & 63;
    if (g >= N_DIS) return;
    float2 r1 = agg_seg(base[g], cnt[g], col, ss_ind, sd_ind[g], Wh_ind, lane);
    float2 r2 = agg_seg(base[40000 + g], cnt[40000 + g], col, ss_dd, sd_dd[g], Wh_dd, lane);
    *(float2*)(out + (size_t)g * D + 2 * lane) = make_float2(r1.x + r2.x, r1.y + r2.y);
}

// h_drug = softmax_agg(rev): one wave per drug node.
__global__ void k_agg_drug(const int* __restrict__ base, const int* __restrict__ cnt,
                           const int* __restrict__ col,
                           const float* __restrict__ ss_rev, const float* __restrict__ sd_rev,
                           const bf16* __restrict__ Wh_rev,
                           float* __restrict__ out)
{
    const int g    = (int)((blockIdx.x * blockDim.x + threadIdx.x) >> 6);
    const int lane = threadIdx.x & 63;
    if (g >= N_DRUG) return;
    float2 r = agg_seg(base[80000 + g], cnt[80000 + g], col, ss_rev, sd_rev[g], Wh_rev, lane);
    *(float2*)(out + (size_t)g * D + 2 * lane) = r;
}

extern "C" void kernel_launch(void* const* d_in, const int* in_sizes, int n_in,
                              void* d_out, int out_size, void* d_ws, size_t ws_size,
                              hipStream_t stream)
{
    const float* feat_drug = (const float*)d_in[0];
    const float* feat_dis  = (const float*)d_in[1];
    const int*   src_ind   = (const int*)d_in[2];
    const int*   dst_ind   = (const int*)d_in[3];
    const int*   src_rev   = (const int*)d_in[4];
    const int*   dst_rev   = (const int*)d_in[5];
    const int*   src_dd    = (const int*)d_in[6];
    const int*   dst_dd    = (const int*)d_in[7];
    const float* W_ind     = (const float*)d_in[8];
    const float* b_ind     = (const float*)d_in[9];
    const float* W_rev     = (const float*)d_in[10];
    const float* b_rev     = (const float*)d_in[11];
    const float* W_dd      = (const float*)d_in[12];
    const float* b_dd      = (const float*)d_in[13];
    const float* a_ind     = (const float*)d_in[14];
    const float* a_rev     = (const float*)d_in[15];
    const float* a_dd      = (const float*)d_in[16];

    float* out_drug = (float*)d_out;                        // [N_DRUG, D] f32
    float* out_dis  = (float*)d_out + (size_t)N_DRUG * D;   // [N_DIS, D]  f32

    char* ws = (char*)d_ws;
    size_t off = 0;
    auto alloc = [&](size_t bytes) -> void* {
        void* p = ws + off;
        off += (bytes + 255) & ~(size_t)255;
        return p;
    };

    bf16* Wh_ind = (bf16*)alloc(sizeof(bf16) * (size_t)N_DRUG * D);
    bf16* Wh_rev = (bf16*)alloc(sizeof(bf16) * (size_t)N_DIS * D);
    bf16* Wh_dd  = (bf16*)alloc(sizeof(bf16) * (size_t)N_DIS * D);

    float* s_src_ind = (float*)alloc(sizeof(float) * N_DRUG);  // Wh_ind . a_ind[:D]
    float* s_dst_rev = (float*)alloc(sizeof(float) * N_DRUG);  // Wh_ind . a_rev[D:]
    float* s_src_rev = (float*)alloc(sizeof(float) * N_DIS);   // Wh_rev . a_rev[:D]
    float* s_dst_ind = (float*)alloc(sizeof(float) * N_DIS);   // Wh_rev . a_ind[D:]
    float* s_src_dd  = (float*)alloc(sizeof(float) * N_DIS);   // Wh_dd  . a_dd[:D]
    float* s_dst_dd  = (float*)alloc(sizeof(float) * N_DIS);   // Wh_dd  . a_dd[D:]

    int* col    = (int*)alloc(sizeof(int) * 3 * NE);   // one pooled col array
    int* base   = (int*)alloc(sizeof(int) * NTOT);
    int* cursor = (int*)alloc(sizeof(int) * NTOT);

    // zero region: cnt[NTOT] | total(+pad)
    const size_t nzero = NTOT + 4;
    int* zr  = (int*)alloc(sizeof(int) * nzero);
    int* cnt = zr;             // ind: [0,40k) | dd: [40k,80k) | rev: [80k,100k)
    int* total = zr + NTOT;

    hipMemsetAsync(zr, 0, sizeof(int) * nzero, stream);

    // --- MFMA projections + per-node attention scalars ---
    k_gemm_mfma<<<(N_DRUG + 63) / 64, 256, 0, stream>>>(feat_drug, N_DRUG, W_ind, b_ind,
                                                        a_ind, a_rev + D, Wh_ind,
                                                        s_src_ind, s_dst_rev);
    k_gemm_mfma<<<(N_DIS + 63) / 64, 256, 0, stream>>>(feat_dis, N_DIS, W_rev, b_rev,
                                                       a_rev, a_ind + D, Wh_rev,
                                                       s_src_rev, s_dst_ind);
    k_gemm_mfma<<<(N_DIS + 63) / 64, 256, 0, stream>>>(feat_dis, N_DIS, W_dd, b_dd,
                                                       a_dd, a_dd + D, Wh_dd,
                                                       s_src_dd, s_dst_dd);

    // --- fused CSR build ---
    const int EB3 = (3 * NE + 255) / 256;
    k_hist3<<<EB3, 256, 0, stream>>>(dst_ind, dst_dd, dst_rev, cnt);
    k_base<<<(NTOT + 255) / 256, 256, 0, stream>>>(cnt, base, cursor, total, NTOT);
    k_fill3<<<EB3, 256, 0, stream>>>(src_ind, dst_ind, src_dd, dst_dd, src_rev, dst_rev,
                                     cursor, col);

    // --- fused gather aggregations ---
    k_agg_dis<<<(N_DIS + 3) / 4, 256, 0, stream>>>(base, cnt, col,
                                                   s_src_ind, s_dst_ind, Wh_ind,
                                                   s_src_dd, s_dst_dd, Wh_dd,
                                                   out_dis);
    k_agg_drug<<<(N_DRUG + 3) / 4, 256, 0, stream>>>(base, cnt, col,
                                                     s_src_rev, s_dst_rev, Wh_rev,
                                                     out_drug);
}

// Round 7
// 368.263 us; speedup vs baseline: 1.1252x; 1.1252x over previous
//
#include <hip/hip_runtime.h>
#include <hip/hip_bf16.h>

#define N_DRUG 20000
#define N_DIS  40000
#define NE     500000
#define D      128
#define PITCH  136     // bf16 elems per LDS row (16B-aligned; 2-way bank alias = free)
#define NTOT   100000  // concatenated node slots: ind(40k) | dd(40k) | rev(20k)

typedef __hip_bfloat16 bf16;
typedef __attribute__((ext_vector_type(8))) short short8;
typedef __attribute__((ext_vector_type(4))) float floatx4;

__device__ __forceinline__ float b2f(bf16 x) { return __bfloat162float(x); }

// MFMA GEMM: Wh(bf16) = feat(f32->bf16) @ W(f32->bf16) + b, plus per-row scalars
// s1 = Wh . a1, s2 = Wh . a2. Block = 256 thr (4 waves) = 64 rows x 128 cols.
__global__ void k_gemm_mfma(const float* __restrict__ feat, int M,
                            const float* __restrict__ W, const float* __restrict__ bias,
                            const float* __restrict__ a1, const float* __restrict__ a2,
                            bf16* __restrict__ Wh, float* __restrict__ s1,
                            float* __restrict__ s2)
{
    __shared__ __align__(16) bf16 WT[128 * PITCH];  // WT[n][k] = W[k][n]
    __shared__ __align__(16) bf16 FS[64 * PITCH];   // FS[r][k] = feat[row0+r][k]
    const int tid  = threadIdx.x;
    const int row0 = blockIdx.x * 64;

#pragma unroll 4
    for (int rep = 0; rep < 64; ++rep) {
        int idx = rep * 256 + tid;           // k*128+n
        int k = idx >> 7, n = idx & 127;
        WT[n * PITCH + k] = __float2bfloat16(W[idx]);
    }
#pragma unroll 4
    for (int rep = 0; rep < 32; ++rep) {
        int idx = rep * 256 + tid;           // r*128+k
        int r = idx >> 7, k = idx & 127;
        int gr = row0 + r;
        float v = (gr < M) ? feat[(size_t)gr * D + k] : 0.f;
        FS[r * PITCH + k] = __float2bfloat16(v);
    }
    __syncthreads();

    const int wave = tid >> 6;
    const int lane = tid & 63;
    const int m0   = wave * 16;
    const int arow = lane & 15;
    const int kq   = lane >> 4;

    floatx4 acc[8];
#pragma unroll
    for (int t = 0; t < 8; ++t) acc[t] = (floatx4){0.f, 0.f, 0.f, 0.f};

#pragma unroll
    for (int ks = 0; ks < 4; ++ks) {
        const int kb = ks * 32 + kq * 8;
        short8 afrag = *(const short8*)(FS + (m0 + arow) * PITCH + kb);
#pragma unroll
        for (int t = 0; t < 8; ++t) {
            short8 bfrag = *(const short8*)(WT + (t * 16 + arow) * PITCH + kb);
            acc[t] = __builtin_amdgcn_mfma_f32_16x16x32_bf16(afrag, bfrag, acc[t], 0, 0, 0);
        }
    }

    const int crow = m0 + kq * 4;
    float p1[4] = {0.f, 0.f, 0.f, 0.f};
    float p2[4] = {0.f, 0.f, 0.f, 0.f};
#pragma unroll
    for (int t = 0; t < 8; ++t) {
        const int n = t * 16 + arow;
        const float bn = bias[n], a1n = a1[n], a2n = a2[n];
#pragma unroll
        for (int r = 0; r < 4; ++r) {
            float v = acc[t][r] + bn;
            int gr = row0 + crow + r;
            if (gr < M) Wh[(size_t)gr * D + n] = __float2bfloat16(v);
            p1[r] += v * a1n;
            p2[r] += v * a2n;
        }
    }
#pragma unroll
    for (int r = 0; r < 4; ++r) {
#pragma unroll
        for (int off = 1; off < 16; off <<= 1) {
            p1[r] += __shfl_xor(p1[r], off);
            p2[r] += __shfl_xor(p2[r], off);
        }
    }
    if (arow == 0) {
#pragma unroll
        for (int r = 0; r < 4; ++r) {
            int gr = row0 + crow + r;
            if (gr < M) { s1[gr] = p1[r]; s2[gr] = p2[r]; }
        }
    }
}

// Fused histogram, int4-vectorized: thread handles 4 edges of one etype.
#define NQ (NE / 4)
__global__ void k_hist3(const int4* __restrict__ d_ind, const int4* __restrict__ d_dd,
                        const int4* __restrict__ d_rev, int* __restrict__ cnt)
{
    int i = blockIdx.x * blockDim.x + threadIdx.x;
    int4 v; int boff;
    if (i < NQ)          { v = d_ind[i];          boff = 0; }
    else if (i < 2 * NQ) { v = d_dd[i - NQ];      boff = 40000; }
    else if (i < 3 * NQ) { v = d_rev[i - 2 * NQ]; boff = 80000; }
    else return;
    atomicAdd(&cnt[boff + v.x], 1);
    atomicAdd(&cnt[boff + v.y], 1);
    atomicAdd(&cnt[boff + v.z], 1);
    atomicAdd(&cnt[boff + v.w], 1);
}

// One scan over the concatenated cnt (segment order arbitrary -> single cursor).
__global__ void k_base(const int* __restrict__ cnt, int* __restrict__ base,
                       int* __restrict__ cursor, int* __restrict__ total, int n)
{
    __shared__ int sd[256];
    __shared__ int sbase;
    const int tid = threadIdx.x;
    const int gid = blockIdx.x * 256 + tid;
    int c = (gid < n) ? cnt[gid] : 0;
    sd[tid] = c;
    __syncthreads();
    for (int off = 1; off < 256; off <<= 1) {
        int v = (tid >= off) ? sd[tid - off] : 0;
        __syncthreads();
        sd[tid] += v;
        __syncthreads();
    }
    if (tid == 255) sbase = atomicAdd(total, sd[255]);
    __syncthreads();
    if (gid < n) {
        int b = sbase + sd[tid] - c;
        base[gid]   = b;
        cursor[gid] = b;
    }
}

// Fused CSR fill, int4-vectorized; col payload is ushort (all ids < 2^16):
// halves scatter footprint and the non-coherent-L2 dirty-line writeback.
__global__ void k_fill3(const int4* __restrict__ s_ind, const int4* __restrict__ d_ind,
                        const int4* __restrict__ s_dd,  const int4* __restrict__ d_dd,
                        const int4* __restrict__ s_rev, const int4* __restrict__ d_rev,
                        int* __restrict__ cursor, unsigned short* __restrict__ col)
{
    int i = blockIdx.x * blockDim.x + threadIdx.x;
    int4 s, d; int boff;
    if (i < NQ)          { s = s_ind[i];          d = d_ind[i];          boff = 0; }
    else if (i < 2 * NQ) { s = s_dd[i - NQ];      d = d_dd[i - NQ];      boff = 40000; }
    else if (i < 3 * NQ) { s = s_rev[i - 2 * NQ]; d = d_rev[i - 2 * NQ]; boff = 80000; }
    else return;
    int p0 = atomicAdd(&cursor[boff + d.x], 1);
    int p1 = atomicAdd(&cursor[boff + d.y], 1);
    int p2 = atomicAdd(&cursor[boff + d.z], 1);
    int p3 = atomicAdd(&cursor[boff + d.w], 1);
    col[p0] = (unsigned short)s.x;
    col[p1] = (unsigned short)s.y;
    col[p2] = (unsigned short)s.z;
    col[p3] = (unsigned short)s.w;
}

// Softmax-weighted gather over one CSR segment; 64-edge batches, 8 gather
// loads in flight. Lane owns 2 output dims.
__device__ __forceinline__ float2 agg_seg(int b, int c, const unsigned short* __restrict__ col,
                                          const float* __restrict__ ssrc, float sdv,
                                          const bf16* __restrict__ Whs, int lane)
{
    float ax = 0.f, ay = 0.f, dpart = 0.f;
    for (int t0 = 0; t0 < c; t0 += 64) {
        const int rem = c - t0;
        const int k = rem < 64 ? rem : 64;
        int myc = 0; float myex = 0.f;   // inactive lanes: exactly 0 contribution
        if (lane < k) {
            myc = col[b + t0 + lane];
            float e = ssrc[myc] + sdv;
            e = (e >= 0.f) ? e : 0.01f * e;
            myex = __expf(fminf(e, 30.f));
        }
        dpart += myex;
        const int kk = (k + 7) & ~7;
        for (int j = 0; j < kk; j += 8) {
            int sv[8]; float ev[8]; __hip_bfloat162 w[8];
#pragma unroll
            for (int u = 0; u < 8; ++u) {
                sv[u] = __shfl(myc, j + u);
                ev[u] = __shfl(myex, j + u);
            }
#pragma unroll
            for (int u = 0; u < 8; ++u)
                w[u] = *(const __hip_bfloat162*)(Whs + (size_t)sv[u] * D + 2 * lane);
#pragma unroll
            for (int u = 0; u < 8; ++u) {
                ax += ev[u] * b2f(w[u].x);
                ay += ev[u] * b2f(w[u].y);
            }
        }
    }
    float denom = dpart;
#pragma unroll
    for (int off = 32; off; off >>= 1) denom += __shfl_xor(denom, off);
    const float inv = (c > 0) ? 1.f / denom : 0.f;
    return make_float2(ax * inv, ay * inv);
}

// One wave per output node: g<N_DIS -> h_dis (ind+dd fused), else -> h_drug.
__global__ void k_agg(const int* __restrict__ base, const int* __restrict__ cnt,
                      const unsigned short* __restrict__ col,
                      const float* __restrict__ ss_ind, const float* __restrict__ sd_ind,
                      const bf16* __restrict__ Wh_ind,
                      const float* __restrict__ ss_dd, const float* __restrict__ sd_dd,
                      const bf16* __restrict__ Wh_dd,
                      const float* __restrict__ ss_rev, const float* __restrict__ sd_rev,
                      const bf16* __restrict__ Wh_rev,
                      float* __restrict__ out_dis, float* __restrict__ out_drug)
{
    const int g    = (int)((blockIdx.x * blockDim.x + threadIdx.x) >> 6);
    const int lane = threadIdx.x & 63;
    if (g < N_DIS) {
        float2 r1 = agg_seg(base[g], cnt[g], col, ss_ind, sd_ind[g], Wh_ind, lane);
        float2 r2 = agg_seg(base[40000 + g], cnt[40000 + g], col, ss_dd, sd_dd[g], Wh_dd, lane);
        *(float2*)(out_dis + (size_t)g * D + 2 * lane) = make_float2(r1.x + r2.x, r1.y + r2.y);
    } else if (g < N_DIS + N_DRUG) {
        const int gg = g - N_DIS;
        float2 r = agg_seg(base[80000 + gg], cnt[80000 + gg], col, ss_rev, sd_rev[gg], Wh_rev, lane);
        *(float2*)(out_drug + (size_t)gg * D + 2 * lane) = r;
    }
}

extern "C" void kernel_launch(void* const* d_in, const int* in_sizes, int n_in,
                              void* d_out, int out_size, void* d_ws, size_t ws_size,
                              hipStream_t stream)
{
    const float* feat_drug = (const float*)d_in[0];
    const float* feat_dis  = (const float*)d_in[1];
    const int*   src_ind   = (const int*)d_in[2];
    const int*   dst_ind   = (const int*)d_in[3];
    const int*   src_rev   = (const int*)d_in[4];
    const int*   dst_rev   = (const int*)d_in[5];
    const int*   src_dd    = (const int*)d_in[6];
    const int*   dst_dd    = (const int*)d_in[7];
    const float* W_ind     = (const float*)d_in[8];
    const float* b_ind     = (const float*)d_in[9];
    const float* W_rev     = (const float*)d_in[10];
    const float* b_rev     = (const float*)d_in[11];
    const float* W_dd      = (const float*)d_in[12];
    const float* b_dd      = (const float*)d_in[13];
    const float* a_ind     = (const float*)d_in[14];
    const float* a_rev     = (const float*)d_in[15];
    const float* a_dd      = (const float*)d_in[16];

    float* out_drug = (float*)d_out;                        // [N_DRUG, D] f32
    float* out_dis  = (float*)d_out + (size_t)N_DRUG * D;   // [N_DIS, D]  f32

    char* ws = (char*)d_ws;
    size_t off = 0;
    auto alloc = [&](size_t bytes) -> void* {
        void* p = ws + off;
        off += (bytes + 255) & ~(size_t)255;
        return p;
    };

    bf16* Wh_ind = (bf16*)alloc(sizeof(bf16) * (size_t)N_DRUG * D);
    bf16* Wh_rev = (bf16*)alloc(sizeof(bf16) * (size_t)N_DIS * D);
    bf16* Wh_dd  = (bf16*)alloc(sizeof(bf16) * (size_t)N_DIS * D);

    float* s_src_ind = (float*)alloc(sizeof(float) * N_DRUG);  // Wh_ind . a_ind[:D]
    float* s_dst_rev = (float*)alloc(sizeof(float) * N_DRUG);  // Wh_ind . a_rev[D:]
    float* s_src_rev = (float*)alloc(sizeof(float) * N_DIS);   // Wh_rev . a_rev[:D]
    float* s_dst_ind = (float*)alloc(sizeof(float) * N_DIS);   // Wh_rev . a_ind[D:]
    float* s_src_dd  = (float*)alloc(sizeof(float) * N_DIS);   // Wh_dd  . a_dd[:D]
    float* s_dst_dd  = (float*)alloc(sizeof(float) * N_DIS);   // Wh_dd  . a_dd[D:]

    unsigned short* col = (unsigned short*)alloc(sizeof(unsigned short) * 3 * NE);
    int* base   = (int*)alloc(sizeof(int) * NTOT);
    int* cursor = (int*)alloc(sizeof(int) * NTOT);

    // zero region: cnt[NTOT] | total(+pad)
    const size_t nzero = NTOT + 4;
    int* zr  = (int*)alloc(sizeof(int) * nzero);
    int* cnt = zr;             // ind: [0,40k) | dd: [40k,80k) | rev: [80k,100k)
    int* total = zr + NTOT;

    hipMemsetAsync(zr, 0, sizeof(int) * nzero, stream);

    // --- MFMA projections + per-node attention scalars ---
    k_gemm_mfma<<<(N_DRUG + 63) / 64, 256, 0, stream>>>(feat_drug, N_DRUG, W_ind, b_ind,
                                                        a_ind, a_rev + D, Wh_ind,
                                                        s_src_ind, s_dst_rev);
    k_gemm_mfma<<<(N_DIS + 63) / 64, 256, 0, stream>>>(feat_dis, N_DIS, W_rev, b_rev,
                                                       a_rev, a_ind + D, Wh_rev,
                                                       s_src_rev, s_dst_ind);
    k_gemm_mfma<<<(N_DIS + 63) / 64, 256, 0, stream>>>(feat_dis, N_DIS, W_dd, b_dd,
                                                       a_dd, a_dd + D, Wh_dd,
                                                       s_src_dd, s_dst_dd);

    // --- fused CSR build (int4 loads, ushort col) ---
    const int EBV = (3 * NQ + 255) / 256;
    k_hist3<<<EBV, 256, 0, stream>>>((const int4*)dst_ind, (const int4*)dst_dd,
                                     (const int4*)dst_rev, cnt);
    k_base<<<(NTOT + 255) / 256, 256, 0, stream>>>(cnt, base, cursor, total, NTOT);
    k_fill3<<<EBV, 256, 0, stream>>>((const int4*)src_ind, (const int4*)dst_ind,
                                     (const int4*)src_dd, (const int4*)dst_dd,
                                     (const int4*)src_rev, (const int4*)dst_rev,
                                     cursor, col);

    // --- fused gather aggregation: 60k waves cover dis then drug ---
    k_agg<<<(N_DIS + N_DRUG + 3) / 4, 256, 0, stream>>>(base, cnt, col,
                                                        s_src_ind, s_dst_ind, Wh_ind,
                                                        s_src_dd, s_dst_dd, Wh_dd,
                                                        s_src_rev, s_dst_rev, Wh_rev,
                                                        out_dis, out_drug);
}

// Round 8
// 356.535 us; speedup vs baseline: 1.1622x; 1.0329x over previous
//
#include <hip/hip_runtime.h>
#include <hip/hip_bf16.h>

#define N_DRUG 20000
#define N_DIS  40000
#define NE     500000
#define D      128
#define PITCH  136     // bf16 elems per LDS row (16B-aligned; 2-way bank alias = free)
#define NTOT   100000  // concatenated node slots: ind(40k) | dd(40k) | rev(20k)
#define NQ     (NE / 4)
#define NQ3    (3 * NQ)
#define PART_SZ (NTOT / 8)   // 12500 concat ids per XCD partition
#define SL     256           // slices per partition (grid = 8*SL blocks)

typedef __hip_bfloat16 bf16;
typedef __attribute__((ext_vector_type(8))) short short8;
typedef __attribute__((ext_vector_type(4))) float floatx4;

__device__ __forceinline__ float b2f(bf16 x) { return __bfloat162float(x); }

// ---- fused MFMA GEMM: all 3 projections in one dispatch ----
// Per 64-row block: Wh(bf16) = feat @ W + b; s1 = Wh.a1; s2 = Wh.a2.
#define GB_DRUG 313   // ceil(20000/64)
#define GB_DIS  625   // 40000/64
__global__ void k_gemm_all(const float* __restrict__ feat_drug, const float* __restrict__ feat_dis,
                           const float* __restrict__ W_ind, const float* __restrict__ b_ind,
                           const float* __restrict__ W_rev, const float* __restrict__ b_rev,
                           const float* __restrict__ W_dd,  const float* __restrict__ b_dd,
                           const float* __restrict__ a_ind, const float* __restrict__ a_rev,
                           const float* __restrict__ a_dd,
                           bf16* __restrict__ Wh_ind, bf16* __restrict__ Wh_rev,
                           bf16* __restrict__ Wh_dd,
                           float* __restrict__ s_src_ind, float* __restrict__ s_dst_rev,
                           float* __restrict__ s_src_rev, float* __restrict__ s_dst_ind,
                           float* __restrict__ s_src_dd,  float* __restrict__ s_dst_dd)
{
    const float *feat, *W, *bias, *a1, *a2;
    bf16* Wh; float *s1, *s2;
    int M, row0;
    const int blk = blockIdx.x;
    if (blk < GB_DRUG) {
        feat = feat_drug; M = N_DRUG; row0 = blk * 64;
        W = W_ind; bias = b_ind; a1 = a_ind; a2 = a_rev + D;
        Wh = Wh_ind; s1 = s_src_ind; s2 = s_dst_rev;
    } else if (blk < GB_DRUG + GB_DIS) {
        feat = feat_dis; M = N_DIS; row0 = (blk - GB_DRUG) * 64;
        W = W_rev; bias = b_rev; a1 = a_rev; a2 = a_ind + D;
        Wh = Wh_rev; s1 = s_src_rev; s2 = s_dst_ind;
    } else {
        feat = feat_dis; M = N_DIS; row0 = (blk - GB_DRUG - GB_DIS) * 64;
        W = W_dd; bias = b_dd; a1 = a_dd; a2 = a_dd + D;
        Wh = Wh_dd; s1 = s_src_dd; s2 = s_dst_dd;
    }

    __shared__ __align__(16) bf16 WT[128 * PITCH];  // WT[n][k] = W[k][n]
    __shared__ __align__(16) bf16 FS[64 * PITCH];   // FS[r][k] = feat[row0+r][k]
    const int tid = threadIdx.x;

#pragma unroll 4
    for (int rep = 0; rep < 64; ++rep) {
        int idx = rep * 256 + tid;           // k*128+n
        int k = idx >> 7, n = idx & 127;
        WT[n * PITCH + k] = __float2bfloat16(W[idx]);
    }
#pragma unroll 4
    for (int rep = 0; rep < 32; ++rep) {
        int idx = rep * 256 + tid;           // r*128+k
        int r = idx >> 7, k = idx & 127;
        int gr = row0 + r;
        float v = (gr < M) ? feat[(size_t)gr * D + k] : 0.f;
        FS[r * PITCH + k] = __float2bfloat16(v);
    }
    __syncthreads();

    const int wave = tid >> 6;
    const int lane = tid & 63;
    const int m0   = wave * 16;
    const int arow = lane & 15;
    const int kq   = lane >> 4;

    floatx4 acc[8];
#pragma unroll
    for (int t = 0; t < 8; ++t) acc[t] = (floatx4){0.f, 0.f, 0.f, 0.f};

#pragma unroll
    for (int ks = 0; ks < 4; ++ks) {
        const int kb = ks * 32 + kq * 8;
        short8 afrag = *(const short8*)(FS + (m0 + arow) * PITCH + kb);
#pragma unroll
        for (int t = 0; t < 8; ++t) {
            short8 bfrag = *(const short8*)(WT + (t * 16 + arow) * PITCH + kb);
            acc[t] = __builtin_amdgcn_mfma_f32_16x16x32_bf16(afrag, bfrag, acc[t], 0, 0, 0);
        }
    }

    const int crow = m0 + kq * 4;
    float p1[4] = {0.f, 0.f, 0.f, 0.f};
    float p2[4] = {0.f, 0.f, 0.f, 0.f};
#pragma unroll
    for (int t = 0; t < 8; ++t) {
        const int n = t * 16 + arow;
        const float bn = bias[n], a1n = a1[n], a2n = a2[n];
#pragma unroll
        for (int r = 0; r < 4; ++r) {
            float v = acc[t][r] + bn;
            int gr = row0 + crow + r;
            if (gr < M) Wh[(size_t)gr * D + n] = __float2bfloat16(v);
            p1[r] += v * a1n;
            p2[r] += v * a2n;
        }
    }
#pragma unroll
    for (int r = 0; r < 4; ++r) {
#pragma unroll
        for (int off = 1; off < 16; off <<= 1) {
            p1[r] += __shfl_xor(p1[r], off);
            p2[r] += __shfl_xor(p2[r], off);
        }
    }
    if (arow == 0) {
#pragma unroll
        for (int r = 0; r < 4; ++r) {
            int gr = row0 + crow + r;
            if (gr < M) { s1[gr] = p1[r]; s2[gr] = p2[r]; }
        }
    }
}

// ---- XCD-partitioned CSR build ----
// block b: part = b&7 (intended XCD via round-robin dispatch), slice = b>>3.
// Each part scans ALL edges (L3-served re-read) but only touches cnt/cursor/col
// for concat ids in [part*PART_SZ, (part+1)*PART_SZ): every cache line of the
// scatter targets is dirtied by exactly one XCD -> no cross-XCD writeback storm.
__global__ void k_hist3x(const int4* __restrict__ d_ind, const int4* __restrict__ d_dd,
                         const int4* __restrict__ d_rev, int* __restrict__ cnt)
{
    const int part = blockIdx.x & 7;
    const int slice = blockIdx.x >> 3;
    const int lo = part * PART_SZ, hi = lo + PART_SZ;
    for (int i = slice * 256 + threadIdx.x; i < NQ3; i += SL * 256) {
        int4 d; int boff;
        if (i < NQ)          { d = d_ind[i];          boff = 0; }
        else if (i < 2 * NQ) { d = d_dd[i - NQ];      boff = 40000; }
        else                 { d = d_rev[i - 2 * NQ]; boff = 80000; }
        int x0 = boff + d.x, x1 = boff + d.y, x2 = boff + d.z, x3 = boff + d.w;
        if (x0 >= lo && x0 < hi) atomicAdd(&cnt[x0], 1);
        if (x1 >= lo && x1 < hi) atomicAdd(&cnt[x1], 1);
        if (x2 >= lo && x2 < hi) atomicAdd(&cnt[x2], 1);
        if (x3 >= lo && x3 < hi) atomicAdd(&cnt[x3], 1);
    }
}

// One scan over the concatenated cnt (segment order arbitrary -> single cursor).
__global__ void k_base(const int* __restrict__ cnt, int* __restrict__ base,
                       int* __restrict__ cursor, int* __restrict__ total, int n)
{
    __shared__ int sd[256];
    __shared__ int sbase;
    const int tid = threadIdx.x;
    const int gid = blockIdx.x * 256 + tid;
    int c = (gid < n) ? cnt[gid] : 0;
    sd[tid] = c;
    __syncthreads();
    for (int off = 1; off < 256; off <<= 1) {
        int v = (tid >= off) ? sd[tid - off] : 0;
        __syncthreads();
        sd[tid] += v;
        __syncthreads();
    }
    if (tid == 255) sbase = atomicAdd(total, sd[255]);
    __syncthreads();
    if (gid < n) {
        int b = sbase + sd[tid] - c;
        base[gid]   = b;
        cursor[gid] = b;
    }
}

__global__ void k_fill3x(const int4* __restrict__ s_ind, const int4* __restrict__ d_ind,
                         const int4* __restrict__ s_dd,  const int4* __restrict__ d_dd,
                         const int4* __restrict__ s_rev, const int4* __restrict__ d_rev,
                         int* __restrict__ cursor, unsigned short* __restrict__ col)
{
    const int part = blockIdx.x & 7;
    const int slice = blockIdx.x >> 3;
    const int lo = part * PART_SZ, hi = lo + PART_SZ;
    for (int i = slice * 256 + threadIdx.x; i < NQ3; i += SL * 256) {
        int4 d; const int4* sp; int j, boff;
        if (i < NQ)          { j = i;          d = d_ind[j]; sp = s_ind; boff = 0; }
        else if (i < 2 * NQ) { j = i - NQ;     d = d_dd[j];  sp = s_dd;  boff = 40000; }
        else                 { j = i - 2 * NQ; d = d_rev[j]; sp = s_rev; boff = 80000; }
        int x0 = boff + d.x, x1 = boff + d.y, x2 = boff + d.z, x3 = boff + d.w;
        bool in0 = (x0 >= lo && x0 < hi), in1 = (x1 >= lo && x1 < hi);
        bool in2 = (x2 >= lo && x2 < hi), in3 = (x3 >= lo && x3 < hi);
        if (in0 | in1 | in2 | in3) {
            int4 s = sp[j];
            if (in0) { int p = atomicAdd(&cursor[x0], 1); col[p] = (unsigned short)s.x; }
            if (in1) { int p = atomicAdd(&cursor[x1], 1); col[p] = (unsigned short)s.y; }
            if (in2) { int p = atomicAdd(&cursor[x2], 1); col[p] = (unsigned short)s.z; }
            if (in3) { int p = atomicAdd(&cursor[x3], 1); col[p] = (unsigned short)s.w; }
        }
    }
}

// ---- softmax-weighted gather aggregation ----
__device__ __forceinline__ float2 agg_seg(int b, int c, const unsigned short* __restrict__ col,
                                          const float* __restrict__ ssrc, float sdv,
                                          const bf16* __restrict__ Whs, int lane)
{
    float ax = 0.f, ay = 0.f, dpart = 0.f;
    for (int t0 = 0; t0 < c; t0 += 64) {
        const int rem = c - t0;
        const int k = rem < 64 ? rem : 64;
        int myc = 0; float myex = 0.f;   // inactive lanes: exactly 0 contribution
        if (lane < k) {
            myc = col[b + t0 + lane];
            float e = ssrc[myc] + sdv;
            e = (e >= 0.f) ? e : 0.01f * e;
            myex = __expf(fminf(e, 30.f));
        }
        dpart += myex;
        const int kk = (k + 7) & ~7;
        for (int j = 0; j < kk; j += 8) {
            int sv[8]; float ev[8]; __hip_bfloat162 w[8];
#pragma unroll
            for (int u = 0; u < 8; ++u) {
                sv[u] = __shfl(myc, j + u);
                ev[u] = __shfl(myex, j + u);
            }
#pragma unroll
            for (int u = 0; u < 8; ++u)
                w[u] = *(const __hip_bfloat162*)(Whs + (size_t)sv[u] * D + 2 * lane);
#pragma unroll
            for (int u = 0; u < 8; ++u) {
                ax += ev[u] * b2f(w[u].x);
                ay += ev[u] * b2f(w[u].y);
            }
        }
    }
    float denom = dpart;
#pragma unroll
    for (int off = 32; off; off >>= 1) denom += __shfl_xor(denom, off);
    const float inv = (c > 0) ? 1.f / denom : 0.f;
    return make_float2(ax * inv, ay * inv);
}

// One wave per output node: g<N_DIS -> h_dis (ind+dd fused), else -> h_drug.
__global__ void k_agg(const int* __restrict__ base, const int* __restrict__ cnt,
                      const unsigned short* __restrict__ col,
                      const float* __restrict__ ss_ind, const float* __restrict__ sd_ind,
                      const bf16* __restrict__ Wh_ind,
                      const float* __restrict__ ss_dd, const float* __restrict__ sd_dd,
                      const bf16* __restrict__ Wh_dd,
                      const float* __restrict__ ss_rev, const float* __restrict__ sd_rev,
                      const bf16* __restrict__ Wh_rev,
                      float* __restrict__ out_dis, float* __restrict__ out_drug)
{
    const int g    = (int)((blockIdx.x * blockDim.x + threadIdx.x) >> 6);
    const int lane = threadIdx.x & 63;
    if (g < N_DIS) {
        float2 r1 = agg_seg(base[g], cnt[g], col, ss_ind, sd_ind[g], Wh_ind, lane);
        float2 r2 = agg_seg(base[40000 + g], cnt[40000 + g], col, ss_dd, sd_dd[g], Wh_dd, lane);
        *(float2*)(out_dis + (size_t)g * D + 2 * lane) = make_float2(r1.x + r2.x, r1.y + r2.y);
    } else if (g < N_DIS + N_DRUG) {
        const int gg = g - N_DIS;
        float2 r = agg_seg(base[80000 + gg], cnt[80000 + gg], col, ss_rev, sd_rev[gg], Wh_rev, lane);
        *(float2*)(out_drug + (size_t)gg * D + 2 * lane) = r;
    }
}

extern "C" void kernel_launch(void* const* d_in, const int* in_sizes, int n_in,
                              void* d_out, int out_size, void* d_ws, size_t ws_size,
                              hipStream_t stream)
{
    const float* feat_drug = (const float*)d_in[0];
    const float* feat_dis  = (const float*)d_in[1];
    const int*   src_ind   = (const int*)d_in[2];
    const int*   dst_ind   = (const int*)d_in[3];
    const int*   src_rev   = (const int*)d_in[4];
    const int*   dst_rev   = (const int*)d_in[5];
    const int*   src_dd    = (const int*)d_in[6];
    const int*   dst_dd    = (const int*)d_in[7];
    const float* W_ind     = (const float*)d_in[8];
    const float* b_ind     = (const float*)d_in[9];
    const float* W_rev     = (const float*)d_in[10];
    const float* b_rev     = (const float*)d_in[11];
    const float* W_dd      = (const float*)d_in[12];
    const float* b_dd      = (const float*)d_in[13];
    const float* a_ind     = (const float*)d_in[14];
    const float* a_rev     = (const float*)d_in[15];
    const float* a_dd      = (const float*)d_in[16];

    float* out_drug = (float*)d_out;                        // [N_DRUG, D] f32
    float* out_dis  = (float*)d_out + (size_t)N_DRUG * D;   // [N_DIS, D]  f32

    char* ws = (char*)d_ws;
    size_t off = 0;
    auto alloc = [&](size_t bytes) -> void* {
        void* p = ws + off;
        off += (bytes + 255) & ~(size_t)255;
        return p;
    };

    bf16* Wh_ind = (bf16*)alloc(sizeof(bf16) * (size_t)N_DRUG * D);
    bf16* Wh_rev = (bf16*)alloc(sizeof(bf16) * (size_t)N_DIS * D);
    bf16* Wh_dd  = (bf16*)alloc(sizeof(bf16) * (size_t)N_DIS * D);

    float* s_src_ind = (float*)alloc(sizeof(float) * N_DRUG);
    float* s_dst_rev = (float*)alloc(sizeof(float) * N_DRUG);
    float* s_src_rev = (float*)alloc(sizeof(float) * N_DIS);
    float* s_dst_ind = (float*)alloc(sizeof(float) * N_DIS);
    float* s_src_dd  = (float*)alloc(sizeof(float) * N_DIS);
    float* s_dst_dd  = (float*)alloc(sizeof(float) * N_DIS);

    unsigned short* col = (unsigned short*)alloc(sizeof(unsigned short) * 3 * NE);
    int* base   = (int*)alloc(sizeof(int) * NTOT);
    int* cursor = (int*)alloc(sizeof(int) * NTOT);

    // zero region: cnt[NTOT] | total(+pad)
    const size_t nzero = NTOT + 4;
    int* zr  = (int*)alloc(sizeof(int) * nzero);
    int* cnt = zr;             // ind: [0,40k) | dd: [40k,80k) | rev: [80k,100k)
    int* total = zr + NTOT;

    hipMemsetAsync(zr, 0, sizeof(int) * nzero, stream);

    // --- fused MFMA projections (one dispatch) ---
    k_gemm_all<<<GB_DRUG + 2 * GB_DIS, 256, 0, stream>>>(
        feat_drug, feat_dis, W_ind, b_ind, W_rev, b_rev, W_dd, b_dd,
        a_ind, a_rev, a_dd, Wh_ind, Wh_rev, Wh_dd,
        s_src_ind, s_dst_rev, s_src_rev, s_dst_ind, s_src_dd, s_dst_dd);

    // --- XCD-partitioned CSR build ---
    k_hist3x<<<8 * SL, 256, 0, stream>>>((const int4*)dst_ind, (const int4*)dst_dd,
                                         (const int4*)dst_rev, cnt);
    k_base<<<(NTOT + 255) / 256, 256, 0, stream>>>(cnt, base, cursor, total, NTOT);
    k_fill3x<<<8 * SL, 256, 0, stream>>>((const int4*)src_ind, (const int4*)dst_ind,
                                         (const int4*)src_dd, (const int4*)dst_dd,
                                         (const int4*)src_rev, (const int4*)dst_rev,
                                         cursor, col);

    // --- fused gather aggregation: 60k waves cover dis then drug ---
    k_agg<<<(N_DIS + N_DRUG + 3) / 4, 256, 0, stream>>>(base, cnt, col,
                                                        s_src_ind, s_dst_ind, Wh_ind,
                                                        s_src_dd, s_dst_dd, Wh_dd,
                                                        s_src_rev, s_dst_rev, Wh_rev,
                                                        out_dis, out_drug);
}